// Round 1
// baseline (440.324 us; speedup 1.0000x reference)
//
#include <hip/hip_runtime.h>
#include <hip/hip_bf16.h>

#define Bn 8
#define Cn 256
#define Hn 128
#define Wn 128
#define On 256
#define Kn 3
#define HWn (Hn*Wn)
#define Pn  (Hn*Wn)      // 16384 spatial outputs per batch
#define CKn (Cn*Kn)      // 768 reduction dim

typedef __attribute__((ext_vector_type(8))) short bf16x8;
typedef __attribute__((ext_vector_type(4))) float f32x4;

__device__ __forceinline__ void gload_lds16(const void* g, void* l) {
  __builtin_amdgcn_global_load_lds(
      (__attribute__((address_space(1))) void*)g,
      (__attribute__((address_space(3))) void*)l, 16, 0, 0);
}

__device__ __forceinline__ unsigned short f2bf(float f) {
  unsigned int u = __float_as_uint(f);
  unsigned int r = (u + 0x7fffu + ((u >> 16) & 1u)) >> 16;
  return (unsigned short)r;
}

// ---------------- Phase 1: offset conv (1x3, C=256 -> 6), fp32 ----------------
__global__ __launch_bounds__(256) void k_offsets(
    const float* __restrict__ x, const float* __restrict__ ow,
    const float* __restrict__ ob, float* __restrict__ off) {
  __shared__ float wlds[Cn * 20];   // [c][oc*3+kw], padded to 20/channel
  __shared__ float blds[6];
  for (int i = threadIdx.x; i < 6 * Cn * 3; i += 256) {
    int oc = i / (Cn * 3); int rem = i % (Cn * 3); int c = rem / 3; int kw = rem % 3;
    wlds[c * 20 + oc * 3 + kw] = ow[i];
  }
  if (threadIdx.x < 6) blds[threadIdx.x] = ob[threadIdx.x];
  __syncthreads();
  int idx = blockIdx.x * 256 + threadIdx.x;   // 0..B*P-1
  int b = idx >> 14;
  int p = idx & (Pn - 1);
  int ho = p >> 7, wo = p & 127;
  const float* xb = x + (size_t)b * Cn * HWn + ho * Wn + wo;
  float acc[6] = {0.f, 0.f, 0.f, 0.f, 0.f, 0.f};
  for (int c = 0; c < Cn; ++c) {
    const float* xr = xb + (size_t)c * HWn;
    float xm = (wo > 0) ? xr[-1] : 0.f;
    float x0 = xr[0];
    float xp = (wo < Wn - 1) ? xr[1] : 0.f;
    float xv[3] = {xm, x0, xp};
    const float* wr = &wlds[c * 20];
    #pragma unroll
    for (int oc = 0; oc < 6; ++oc)
      #pragma unroll
      for (int kw = 0; kw < 3; ++kw)
        acc[oc] += xv[kw] * wr[oc * 3 + kw];
  }
  #pragma unroll
  for (int oc = 0; oc < 6; ++oc) {
    float v = (oc == 1 || oc == 4) ? 0.f : (acc[oc] + blds[oc]);
    off[((size_t)b * 6 + oc) * Pn + p] = v;
  }
}

// ---------------- Phase 2a: deform_w fp32 -> bf16 ----------------
__global__ __launch_bounds__(256) void k_wcast(const float* __restrict__ w,
                                               unsigned short* __restrict__ wb) {
  int i = (blockIdx.x * 256 + threadIdx.x) * 4;
  float4 v = *(const float4*)(w + i);
  ushort4 o;
  o.x = f2bf(v.x); o.y = f2bf(v.y); o.z = f2bf(v.z); o.w = f2bf(v.w);
  *(ushort4*)(wb + i) = o;
}

// ---------------- Phase 2b: bilinear sampling -> sampled[p][ck] bf16 ----------------
__global__ __launch_bounds__(256) void k_sample(
    const float* __restrict__ x, const float* __restrict__ off,
    unsigned short* __restrict__ smp, int b) {
  int blk = blockIdx.x;               // 512 blocks: (ho, wo-chunk)
  int ho = blk >> 2;
  int wo0 = (blk & 3) * 32;
  int tid = threadIdx.x;
  int pl = tid & 31;                  // local position
  int csub = tid >> 5;                // 0..7 channel sub-group
  int wo = wo0 + pl;
  int p = ho * Wn + wo;
  __shared__ unsigned short st[32][776];   // [p][768 + 8 pad] -> 1552B rows
  int idx4[3][4];
  float wgt[3][4];
  const float* offb = off + (size_t)b * 6 * Pn;
  #pragma unroll
  for (int k = 0; k < 3; ++k) {
    float oy = offb[(2 * k + 0) * Pn + p];
    float ox = offb[(2 * k + 1) * Pn + p];
    float py = (float)ho + oy;
    float px = (float)(wo + k - 1) + ox;
    float y0f = floorf(py), x0f = floorf(px);
    float wy = py - y0f, wx = px - x0f;
    int y0 = (int)y0f, x0 = (int)x0f;
    int y1 = y0 + 1, x1 = x0 + 1;
    bool vy0 = (y0 >= 0) && (y0 < Hn), vy1 = (y1 >= 0) && (y1 < Hn);
    bool vx0 = (x0 >= 0) && (x0 < Wn), vx1 = (x1 >= 0) && (x1 < Wn);
    int yc0 = min(max(y0, 0), Hn - 1), yc1 = min(max(y1, 0), Hn - 1);
    int xc0 = min(max(x0, 0), Wn - 1), xc1 = min(max(x1, 0), Wn - 1);
    idx4[k][0] = yc0 * Wn + xc0; idx4[k][1] = yc0 * Wn + xc1;
    idx4[k][2] = yc1 * Wn + xc0; idx4[k][3] = yc1 * Wn + xc1;
    wgt[k][0] = (vy0 && vx0) ? (1.f - wy) * (1.f - wx) : 0.f;
    wgt[k][1] = (vy0 && vx1) ? (1.f - wy) * wx : 0.f;
    wgt[k][2] = (vy1 && vx0) ? wy * (1.f - wx) : 0.f;
    wgt[k][3] = (vy1 && vx1) ? wy * wx : 0.f;
  }
  const float* xb = x + (size_t)b * Cn * HWn;
  for (int ci = 0; ci < 32; ++ci) {
    int c = csub * 32 + ci;
    const float* xc = xb + (size_t)c * HWn;
    #pragma unroll
    for (int k = 0; k < 3; ++k) {
      float v = wgt[k][0] * xc[idx4[k][0]] + wgt[k][1] * xc[idx4[k][1]]
              + wgt[k][2] * xc[idx4[k][2]] + wgt[k][3] * xc[idx4[k][3]];
      st[pl][c * 3 + k] = f2bf(v);
    }
  }
  __syncthreads();
  // coalesced write: 32 rows x 1536B contiguous
  char* dst = (char*)smp + (size_t)(ho * Wn + wo0) * (CKn * 2);
  int r = tid >> 3, sub = tid & 7;
  #pragma unroll
  for (int i = 0; i < 12; ++i) {
    int chunk = sub + i * 8;          // 0..95
    float4 v = *(const float4*)((const char*)&st[r][0] + chunk * 16);
    *(float4*)(dst + (size_t)r * 1536 + chunk * 16) = v;
  }
}

// ---------------- Phase 3: GEMM  D[o][p] = sum_ck w[o][ck] * s[p][ck] ----------------
__global__ __launch_bounds__(256) void k_gemm(
    const unsigned short* __restrict__ smp,  // [nb][P][CK] bf16
    const unsigned short* __restrict__ wb,   // [O][CK]  bf16
    float* __restrict__ out, int b0) {
  int bi = blockIdx.x >> 7;
  int mt = blockIdx.x & 127;
  int p0 = mt * 128;
  int o0 = blockIdx.y * 128;
  __shared__ unsigned short Ws[128 * 64];    // [o][64ck] swizzled, 128B rows
  __shared__ unsigned short Ss[128 * 64];    // [p][64ck] swizzled
  int tid = threadIdx.x;
  int lane = tid & 63, wid = tid >> 6;
  int wr = wid >> 1, wc = wid & 1;
  f32x4 acc[4][4];
  #pragma unroll
  for (int m = 0; m < 4; ++m)
    #pragma unroll
    for (int n = 0; n < 4; ++n) acc[m][n] = (f32x4){0.f, 0.f, 0.f, 0.f};

  const unsigned short* sb = smp + (size_t)bi * Pn * CKn;

  for (int kt = 0; kt < 12; ++kt) {
    int ck0 = kt * 64;
    __syncthreads();
    #pragma unroll
    for (int i = 0; i < 4; ++i) {
      int fo = wid * 1024 + i * 4096 + lane * 16;   // wave-uniform base + lane*16
      int row = fo >> 7;
      int slot = (fo >> 4) & 7;
      int ss = slot ^ (row & 7);                    // pre-swizzle the SOURCE (rule 21)
      gload_lds16(wb + (size_t)(o0 + row) * CKn + ck0 + ss * 8, (char*)Ws + fo);
      gload_lds16(sb + (size_t)(p0 + row) * CKn + ck0 + ss * 8, (char*)Ss + fo);
    }
    __syncthreads();
    #pragma unroll
    for (int s = 0; s < 2; ++s) {
      bf16x8 af[4], bfr[4];
      #pragma unroll
      for (int m = 0; m < 4; ++m) {
        int row = wr * 64 + m * 16 + (lane & 15);
        int slot = (s * 4 + (lane >> 4)) ^ (row & 7);
        af[m] = *(const bf16x8*)((const char*)Ws + row * 128 + slot * 16);
      }
      #pragma unroll
      for (int n = 0; n < 4; ++n) {
        int row = wc * 64 + n * 16 + (lane & 15);
        int slot = (s * 4 + (lane >> 4)) ^ (row & 7);
        bfr[n] = *(const bf16x8*)((const char*)Ss + row * 128 + slot * 16);
      }
      #pragma unroll
      for (int m = 0; m < 4; ++m)
        #pragma unroll
        for (int n = 0; n < 4; ++n)
          acc[m][n] = __builtin_amdgcn_mfma_f32_16x16x32_bf16(af[m], bfr[n], acc[m][n], 0, 0, 0);
    }
  }
  int b = b0 + bi;
  float* ob = out + (size_t)b * On * Pn;
  #pragma unroll
  for (int m = 0; m < 4; ++m)
    #pragma unroll
    for (int n = 0; n < 4; ++n)
      #pragma unroll
      for (int r = 0; r < 4; ++r) {
        int o = o0 + wr * 64 + m * 16 + (lane >> 4) * 4 + r;
        int p = p0 + wc * 64 + n * 16 + (lane & 15);
        ob[(size_t)o * Pn + p] = acc[m][n][r];
      }
}

extern "C" void kernel_launch(void* const* d_in, const int* in_sizes, int n_in,
                              void* d_out, int out_size, void* d_ws, size_t ws_size,
                              hipStream_t stream) {
  const float* x  = (const float*)d_in[0];
  const float* ow = (const float*)d_in[1];
  const float* ob = (const float*)d_in[2];
  const float* dw = (const float*)d_in[3];
  float* out = (float*)d_out;

  char* ws = (char*)d_ws;
  size_t off_bytes = (size_t)Bn * 6 * Pn * 4;             // 3.1 MB
  size_t wb_bytes  = (size_t)On * CKn * 2;                // 384 KB
  size_t smp_bytes = (size_t)Pn * CKn * 2;                // 25.2 MB / batch
  size_t off_al = (off_bytes + 255) & ~(size_t)255;
  size_t wb_al  = (wb_bytes + 255) & ~(size_t)255;
  float* off = (float*)ws;
  unsigned short* wbp = (unsigned short*)(ws + off_al);
  unsigned short* smp = (unsigned short*)(ws + off_al + wb_al);
  int nb = (ws_size >= off_al + wb_al + 2 * smp_bytes) ? 2 : 1;

  k_offsets<<<512, 256, 0, stream>>>(x, ow, ob, off);
  k_wcast<<<192, 256, 0, stream>>>(dw, wbp);
  for (int b0 = 0; b0 < Bn; b0 += nb) {
    for (int j = 0; j < nb; ++j)
      k_sample<<<512, 256, 0, stream>>>(x, off, smp + (size_t)j * Pn * CKn, b0 + j);
    k_gemm<<<dim3(nb * 128, 2), 256, 0, stream>>>(smp, wbp, out, b0);
  }
}

// Round 2
// 375.716 us; speedup vs baseline: 1.1720x; 1.1720x over previous
//
#include <hip/hip_runtime.h>
#include <hip/hip_bf16.h>

#define Bn 8
#define Cn 256
#define Hn 128
#define Wn 128
#define On 256
#define Kn 3
#define HWn (Hn*Wn)
#define Pn  (Hn*Wn)      // 16384 spatial outputs per batch
#define CKn (Cn*Kn)      // 768 reduction dim

typedef __attribute__((ext_vector_type(8))) short bf16x8;
typedef __attribute__((ext_vector_type(4))) float f32x4;

__device__ __forceinline__ void gload_lds16(const void* g, void* l) {
  __builtin_amdgcn_global_load_lds(
      (__attribute__((address_space(1))) void*)g,
      (__attribute__((address_space(3))) void*)l, 16, 0, 0);
}

__device__ __forceinline__ unsigned short f2bf(float f) {
  unsigned int u = __float_as_uint(f);
  unsigned int r = (u + 0x7fffu + ((u >> 16) & 1u)) >> 16;
  return (unsigned short)r;
}

// ---------------- Phase 1: offset conv (1x3, C=256 -> 6), fp32 ----------------
// 64 positions/block, C-reduction split 4-way across waves, LDS tree reduce.
__global__ __launch_bounds__(256) void k_offsets(
    const float* __restrict__ x, const float* __restrict__ ow,
    const float* __restrict__ ob, float* __restrict__ off) {
  __shared__ float wlds[Cn * 18];       // [c][oc*3+kw] packed; wave-uniform reads
  __shared__ float red[4 * 64 * 6];
  __shared__ float blds[6];
  for (int i = threadIdx.x; i < 6 * Cn * 3; i += 256) {
    int oc = i / (Cn * 3); int rem = i % (Cn * 3); int c = rem / 3; int kw = rem % 3;
    wlds[c * 18 + oc * 3 + kw] = ow[i];
  }
  if (threadIdx.x < 6) blds[threadIdx.x] = ob[threadIdx.x];
  __syncthreads();

  int tid = threadIdx.x;
  int pos = tid & 63;                   // position within 64-chunk (lane)
  int cs  = tid >> 6;                   // wave id = channel split 0..3
  int blk = blockIdx.x;                 // Bn*256 blocks
  int b   = blk >> 8;
  int ho  = (blk & 255) >> 1;
  int wo0 = (blk & 1) * 64;
  int wo  = wo0 + pos;
  const float* xb = x + (size_t)b * Cn * HWn + ho * Wn + wo;

  float acc[6] = {0.f, 0.f, 0.f, 0.f, 0.f, 0.f};
  for (int ci = 0; ci < 64; ++ci) {
    int c = cs * 64 + ci;
    const float* xr = xb + (size_t)c * HWn;
    float xm = (wo > 0) ? xr[-1] : 0.f;
    float x0 = xr[0];
    float xp = (wo < Wn - 1) ? xr[1] : 0.f;
    float xv[3] = {xm, x0, xp};
    const float* wr = &wlds[c * 18];
    #pragma unroll
    for (int oc = 0; oc < 6; ++oc)
      #pragma unroll
      for (int kw = 0; kw < 3; ++kw)
        acc[oc] += xv[kw] * wr[oc * 3 + kw];
  }

  float* rp = &red[(cs * 64 + pos) * 6];
  if (cs >= 2) {
    #pragma unroll
    for (int oc = 0; oc < 6; ++oc) rp[oc] = acc[oc];
  }
  __syncthreads();
  if (cs < 2) {
    const float* q = &red[((cs + 2) * 64 + pos) * 6];
    #pragma unroll
    for (int oc = 0; oc < 6; ++oc) acc[oc] += q[oc];
    if (cs == 1) {
      #pragma unroll
      for (int oc = 0; oc < 6; ++oc) rp[oc] = acc[oc];
    }
  }
  __syncthreads();
  if (cs == 0) {
    const float* q = &red[(64 + pos) * 6];
    int p = ho * Wn + wo;
    #pragma unroll
    for (int oc = 0; oc < 6; ++oc) {
      float v = acc[oc] + q[oc];
      v = (oc == 1 || oc == 4) ? 0.f : (v + blds[oc]);
      off[((size_t)b * 6 + oc) * Pn + p] = v;
    }
  }
}

// ---------------- Phase 2a: deform_w fp32 -> bf16 ----------------
__global__ __launch_bounds__(256) void k_wcast(const float* __restrict__ w,
                                               unsigned short* __restrict__ wb) {
  int i = (blockIdx.x * 256 + threadIdx.x) * 4;
  float4 v = *(const float4*)(w + i);
  ushort4 o;
  o.x = f2bf(v.x); o.y = f2bf(v.y); o.z = f2bf(v.z); o.w = f2bf(v.w);
  *(ushort4*)(wb + i) = o;
}

// ---------------- Phase 2b: bilinear sampling -> sampled[p][ck] bf16 ----------------
// 16 positions/block, 16-way channel split; batch in blockIdx.y.
__global__ __launch_bounds__(256) void k_sample(
    const float* __restrict__ x, const float* __restrict__ off,
    unsigned short* __restrict__ smp, int b0) {
  int j = blockIdx.y;
  int b = b0 + j;
  unsigned short* sj = smp + (size_t)j * Pn * CKn;
  int blk = blockIdx.x;               // 1024 blocks: (ho, wo-chunk of 16)
  int ho  = blk >> 3;
  int wo0 = (blk & 7) * 16;
  int tid = threadIdx.x;
  int pl   = tid & 15;                // local position
  int csub = tid >> 4;                // 0..15 channel sub-group
  int wo = wo0 + pl;
  int p  = ho * Wn + wo;
  __shared__ unsigned short st[16][776];   // [p][768 + 8 pad]
  int idx4[3][4];
  float wgt[3][4];
  const float* offb = off + (size_t)b * 6 * Pn;
  #pragma unroll
  for (int k = 0; k < 3; ++k) {
    float oy = offb[(2 * k + 0) * Pn + p];
    float ox = offb[(2 * k + 1) * Pn + p];
    float py = (float)ho + oy;
    float px = (float)(wo + k - 1) + ox;
    float y0f = floorf(py), x0f = floorf(px);
    float wy = py - y0f, wx = px - x0f;
    int y0 = (int)y0f, x0 = (int)x0f;
    int y1 = y0 + 1, x1 = x0 + 1;
    bool vy0 = (y0 >= 0) && (y0 < Hn), vy1 = (y1 >= 0) && (y1 < Hn);
    bool vx0 = (x0 >= 0) && (x0 < Wn), vx1 = (x1 >= 0) && (x1 < Wn);
    int yc0 = min(max(y0, 0), Hn - 1), yc1 = min(max(y1, 0), Hn - 1);
    int xc0 = min(max(x0, 0), Wn - 1), xc1 = min(max(x1, 0), Wn - 1);
    idx4[k][0] = yc0 * Wn + xc0; idx4[k][1] = yc0 * Wn + xc1;
    idx4[k][2] = yc1 * Wn + xc0; idx4[k][3] = yc1 * Wn + xc1;
    wgt[k][0] = (vy0 && vx0) ? (1.f - wy) * (1.f - wx) : 0.f;
    wgt[k][1] = (vy0 && vx1) ? (1.f - wy) * wx : 0.f;
    wgt[k][2] = (vy1 && vx0) ? wy * (1.f - wx) : 0.f;
    wgt[k][3] = (vy1 && vx1) ? wy * wx : 0.f;
  }
  const float* xb = x + (size_t)b * Cn * HWn;
  for (int ci = 0; ci < 16; ++ci) {
    int c = csub * 16 + ci;
    const float* xc = xb + (size_t)c * HWn;
    #pragma unroll
    for (int k = 0; k < 3; ++k) {
      float v = wgt[k][0] * xc[idx4[k][0]] + wgt[k][1] * xc[idx4[k][1]]
              + wgt[k][2] * xc[idx4[k][2]] + wgt[k][3] * xc[idx4[k][3]];
      st[pl][c * 3 + k] = f2bf(v);
    }
  }
  __syncthreads();
  // coalesced write: 16 rows x 1536B contiguous
  char* dst = (char*)sj + (size_t)(ho * Wn + wo0) * (CKn * 2);
  int r = tid >> 4, sub = tid & 15;
  #pragma unroll
  for (int i = 0; i < 6; ++i) {
    int chunk = sub + i * 16;         // 0..95
    float4 v = *(const float4*)((const char*)&st[r][0] + chunk * 16);
    *(float4*)(dst + (size_t)r * 1536 + chunk * 16) = v;
  }
}

// ---------------- Phase 3: GEMM  D[o][p] = sum_ck w[o][ck] * s[p][ck] ----------------
__global__ __launch_bounds__(256) void k_gemm(
    const unsigned short* __restrict__ smp,  // [nb][P][CK] bf16
    const unsigned short* __restrict__ wb,   // [O][CK]  bf16
    float* __restrict__ out, int b0) {
  int bi = blockIdx.x >> 7;
  int mt = blockIdx.x & 127;
  int p0 = mt * 128;
  int o0 = blockIdx.y * 128;
  __shared__ unsigned short Ws[128 * 64];    // [o][64ck] swizzled, 128B rows
  __shared__ unsigned short Ss[128 * 64];    // [p][64ck] swizzled
  int tid = threadIdx.x;
  int lane = tid & 63, wid = tid >> 6;
  int wr = wid >> 1, wc = wid & 1;
  f32x4 acc[4][4];
  #pragma unroll
  for (int m = 0; m < 4; ++m)
    #pragma unroll
    for (int n = 0; n < 4; ++n) acc[m][n] = (f32x4){0.f, 0.f, 0.f, 0.f};

  const unsigned short* sb = smp + (size_t)bi * Pn * CKn;

  for (int kt = 0; kt < 12; ++kt) {
    int ck0 = kt * 64;
    __syncthreads();
    #pragma unroll
    for (int i = 0; i < 4; ++i) {
      int fo = wid * 1024 + i * 4096 + lane * 16;   // wave-uniform base + lane*16
      int row = fo >> 7;
      int slot = (fo >> 4) & 7;
      int ss = slot ^ (row & 7);                    // pre-swizzle the SOURCE (rule 21)
      gload_lds16(wb + (size_t)(o0 + row) * CKn + ck0 + ss * 8, (char*)Ws + fo);
      gload_lds16(sb + (size_t)(p0 + row) * CKn + ck0 + ss * 8, (char*)Ss + fo);
    }
    __syncthreads();
    #pragma unroll
    for (int s = 0; s < 2; ++s) {
      bf16x8 af[4], bfr[4];
      #pragma unroll
      for (int m = 0; m < 4; ++m) {
        int row = wr * 64 + m * 16 + (lane & 15);
        int slot = (s * 4 + (lane >> 4)) ^ (row & 7);
        af[m] = *(const bf16x8*)((const char*)Ws + row * 128 + slot * 16);
      }
      #pragma unroll
      for (int n = 0; n < 4; ++n) {
        int row = wc * 64 + n * 16 + (lane & 15);
        int slot = (s * 4 + (lane >> 4)) ^ (row & 7);
        bfr[n] = *(const bf16x8*)((const char*)Ss + row * 128 + slot * 16);
      }
      #pragma unroll
      for (int m = 0; m < 4; ++m)
        #pragma unroll
        for (int n = 0; n < 4; ++n)
          acc[m][n] = __builtin_amdgcn_mfma_f32_16x16x32_bf16(af[m], bfr[n], acc[m][n], 0, 0, 0);
    }
  }
  int b = b0 + bi;
  float* ob = out + (size_t)b * On * Pn;
  #pragma unroll
  for (int m = 0; m < 4; ++m)
    #pragma unroll
    for (int n = 0; n < 4; ++n)
      #pragma unroll
      for (int r = 0; r < 4; ++r) {
        int o = o0 + wr * 64 + m * 16 + (lane >> 4) * 4 + r;
        int p = p0 + wc * 64 + n * 16 + (lane & 15);
        ob[(size_t)o * Pn + p] = acc[m][n][r];
      }
}

extern "C" void kernel_launch(void* const* d_in, const int* in_sizes, int n_in,
                              void* d_out, int out_size, void* d_ws, size_t ws_size,
                              hipStream_t stream) {
  const float* x  = (const float*)d_in[0];
  const float* ow = (const float*)d_in[1];
  const float* ob = (const float*)d_in[2];
  const float* dw = (const float*)d_in[3];
  float* out = (float*)d_out;

  char* ws = (char*)d_ws;
  size_t off_bytes = (size_t)Bn * 6 * Pn * 4;             // 3.1 MB
  size_t wb_bytes  = (size_t)On * CKn * 2;                // 384 KB
  size_t smp_bytes = (size_t)Pn * CKn * 2;                // 25.2 MB / batch
  size_t off_al = (off_bytes + 255) & ~(size_t)255;
  size_t wb_al  = (wb_bytes + 255) & ~(size_t)255;
  float* off = (float*)ws;
  unsigned short* wbp = (unsigned short*)(ws + off_al);
  unsigned short* smp = (unsigned short*)(ws + off_al + wb_al);
  size_t fixed = off_al + wb_al;
  int nb = 1;
  if (ws_size >= fixed + 4 * smp_bytes) nb = 4;
  else if (ws_size >= fixed + 2 * smp_bytes) nb = 2;

  k_offsets<<<Bn * 256, 256, 0, stream>>>(x, ow, ob, off);
  k_wcast<<<192, 256, 0, stream>>>(dw, wbp);
  for (int b0 = 0; b0 < Bn; b0 += nb) {
    k_sample<<<dim3(1024, nb), 256, 0, stream>>>(x, off, smp, b0);
    k_gemm<<<dim3(nb * 128, 2), 256, 0, stream>>>(smp, wbp, out, b0);
  }
}

// Round 3
// 363.302 us; speedup vs baseline: 1.2120x; 1.0342x over previous
//
#include <hip/hip_runtime.h>
#include <hip/hip_bf16.h>

#define Bn 8
#define Cn 256
#define Hn 128
#define Wn 128
#define On 256
#define HWn (Hn*Wn)
#define Pn  HWn           // 16384 positions per batch
#define Rn  786           // 768 deform rows (k*256+o) + 18 offset rows
#define Rpad 896          // 7 * 128 GEMM M-tiles
#define GROW 800          // G2 row length in elements (row = one q)
#define QC  ((size_t)Pn * Cn)

typedef __attribute__((ext_vector_type(8))) short bf16x8;
typedef __attribute__((ext_vector_type(4))) float f32x4;

__device__ __forceinline__ void gload_lds16(const void* g, void* l) {
  __builtin_amdgcn_global_load_lds(
      (__attribute__((address_space(1))) void*)g,
      (__attribute__((address_space(3))) void*)l, 16, 0, 0);
}

__device__ __forceinline__ unsigned short f2bf(float f) {
  unsigned int u = __float_as_uint(f);
  unsigned int r = (u + 0x7fffu + ((u >> 16) & 1u)) >> 16;
  return (unsigned short)r;
}
__device__ __forceinline__ float bf2f(unsigned short u) {
  return __uint_as_float(((unsigned int)u) << 16);
}

// -------- Phase 0: build W_big[r][c] bf16, r = k*256+o (deform) | 768+oc*3+kw (offset), pad->896 --------
__global__ __launch_bounds__(256) void k_wprep(
    const float* __restrict__ dw, const float* __restrict__ ow,
    unsigned short* __restrict__ Wbig) {
  int r = blockIdx.x;          // 0..895
  int c = threadIdx.x;         // 0..255
  float v = 0.f;
  if (r < 768) {
    int k = r >> 8, o = r & 255;
    v = dw[((size_t)o * Cn + c) * 3 + k];
  } else if (r < Rn) {
    int rr = r - 768;
    int oc = rr / 3, kw = rr - 3 * oc;
    v = ow[((size_t)oc * Cn + c) * 3 + kw];
  }
  Wbig[(size_t)r * Cn + c] = f2bf(v);
}

// -------- Phase 1: transpose+cast  xbT[j][q][c] bf16 <- x[b][c][q] fp32 --------
__global__ __launch_bounds__(256) void k_transpose(
    const float* __restrict__ x, unsigned short* __restrict__ xbT, int b0) {
  int b = b0 + blockIdx.z;
  int q0 = blockIdx.x * 64, c0 = blockIdx.y * 64;
  __shared__ unsigned short t[64][66];
  int tid = threadIdx.x;
  int qi = tid & 63, cg = tid >> 6;
  const float* xb = x + (size_t)b * Cn * HWn;
  #pragma unroll
  for (int i = 0; i < 16; ++i) {
    int cl = i * 4 + cg;
    t[cl][qi] = f2bf(xb[(size_t)(c0 + cl) * HWn + q0 + qi]);
  }
  __syncthreads();
  unsigned short* dst = xbT + (size_t)blockIdx.z * QC;
  int c2 = (tid & 31) * 2, qg = tid >> 5;
  #pragma unroll
  for (int j = 0; j < 8; ++j) {
    int ql = j * 8 + qg;
    unsigned int u = (unsigned int)t[c2][ql] | ((unsigned int)t[c2 + 1][ql] << 16);
    *(unsigned int*)(dst + (size_t)(q0 + ql) * Cn + c0 + c2) = u;
  }
}

// -------- Phase 2: GEMM  G2[q][r] = sum_c xbT[q][c] * Wbig[r][c]  (bf16 out) --------
__global__ __launch_bounds__(256) void k_gemmG(
    const unsigned short* __restrict__ xbT,
    const unsigned short* __restrict__ Wbig,
    unsigned short* __restrict__ G2) {
  int q0 = blockIdx.x * 128;
  int r0 = blockIdx.y * 128;
  const unsigned short* xb = xbT + (size_t)blockIdx.z * QC;
  unsigned short* Gz = G2 + (size_t)blockIdx.z * Pn * GROW;
  __shared__ unsigned short Qs[128 * 64];    // [q][64c] swizzled (A-operand)
  __shared__ unsigned short Ws[128 * 64];    // [r][64c] swizzled (B-operand)
  int tid = threadIdx.x;
  int lane = tid & 63, wid = tid >> 6;
  int wr = wid >> 1, wc = wid & 1;           // wr: q-half, wc: r-half
  f32x4 acc[4][4];
  #pragma unroll
  for (int m = 0; m < 4; ++m)
    #pragma unroll
    for (int n = 0; n < 4; ++n) acc[m][n] = (f32x4){0.f, 0.f, 0.f, 0.f};

  for (int kt = 0; kt < 4; ++kt) {
    int ck0 = kt * 64;
    __syncthreads();
    #pragma unroll
    for (int i = 0; i < 4; ++i) {
      int fo = wid * 1024 + i * 4096 + lane * 16;
      int row = fo >> 7;
      int slot = (fo >> 4) & 7;
      int ss = slot ^ (row & 7);             // pre-swizzle SOURCE (rule 21)
      gload_lds16(xb   + (size_t)(q0 + row) * Cn + ck0 + ss * 8, (char*)Qs + fo);
      gload_lds16(Wbig + (size_t)(r0 + row) * Cn + ck0 + ss * 8, (char*)Ws + fo);
    }
    __syncthreads();
    #pragma unroll
    for (int s = 0; s < 2; ++s) {
      bf16x8 af[4], bfr[4];
      #pragma unroll
      for (int m = 0; m < 4; ++m) {
        int row = wr * 64 + m * 16 + (lane & 15);
        int slot = (s * 4 + (lane >> 4)) ^ (row & 7);
        af[m] = *(const bf16x8*)((const char*)Qs + row * 128 + slot * 16);
      }
      #pragma unroll
      for (int n = 0; n < 4; ++n) {
        int row = wc * 64 + n * 16 + (lane & 15);
        int slot = (s * 4 + (lane >> 4)) ^ (row & 7);
        bfr[n] = *(const bf16x8*)((const char*)Ws + row * 128 + slot * 16);
      }
      #pragma unroll
      for (int m = 0; m < 4; ++m)
        #pragma unroll
        for (int n = 0; n < 4; ++n)
          acc[m][n] = __builtin_amdgcn_mfma_f32_16x16x32_bf16(af[m], bfr[n], acc[m][n], 0, 0, 0);
    }
  }
  // D rows = q (A-operand), cols = r (B-operand)
  #pragma unroll
  for (int m = 0; m < 4; ++m)
    #pragma unroll
    for (int n = 0; n < 4; ++n)
      #pragma unroll
      for (int rr = 0; rr < 4; ++rr) {
        int q = q0 + wr * 64 + m * 16 + (lane >> 4) * 4 + rr;
        int r = r0 + wc * 64 + n * 16 + (lane & 15);
        if (r < Rn) Gz[(size_t)q * GROW + r] = f2bf(acc[m][n][rr]);
      }
}

// -------- Phase 3: epilogue  out[b][o][p] = sum_k sum_corner wgt * G2[q_corner][k*256+o] --------
__global__ __launch_bounds__(256) void k_epilogue(
    const unsigned short* __restrict__ G2, const float* __restrict__ obias,
    float* __restrict__ out, int b0) {
  int z = blockIdx.z;
  int b = b0 + z;
  const char* Gb = (const char*)(G2 + (size_t)z * Pn * GROW);
  int p0 = blockIdx.x * 64;
  int o0 = blockIdx.y * 64;
  int ho = p0 >> 7, wo0 = p0 & 127;

  __shared__ float Sw[64][3][4];
  __shared__ int   Sq[64][3][4];
  int tid = threadIdx.x;
  if (tid < 192) {
    int pl = tid & 63, k = tid >> 6;
    int wo = wo0 + pl;
    // offsets from Goff rows (768 + oc*3 + kw), 3-tap combine, + bias; channels 1,4 -> 0
    float offy = 0.f, offx = 0.f;
    int ocy = 2 * k, ocx = 2 * k + 1;
    if (ocy != 4) {
      float s = obias[ocy];
      #pragma unroll
      for (int kw = 0; kw < 3; ++kw) {
        int col = wo + kw - 1;
        if (col >= 0 && col < Wn)
          s += bf2f(*(const unsigned short*)(Gb + ((size_t)(ho * Wn + col) * GROW + 768 + ocy * 3 + kw) * 2));
      }
      offy = s;
    }
    if (ocx != 1) {
      float s = obias[ocx];
      #pragma unroll
      for (int kw = 0; kw < 3; ++kw) {
        int col = wo + kw - 1;
        if (col >= 0 && col < Wn)
          s += bf2f(*(const unsigned short*)(Gb + ((size_t)(ho * Wn + col) * GROW + 768 + ocx * 3 + kw) * 2));
      }
      offx = s;
    }
    float py = (float)ho + offy;
    float px = (float)(wo + k - 1) + offx;
    float y0f = floorf(py), x0f = floorf(px);
    float wy = py - y0f, wx = px - x0f;
    int y0 = (int)y0f, x0 = (int)x0f;
    int y1 = y0 + 1, x1 = x0 + 1;
    bool vy0 = (y0 >= 0) && (y0 < Hn), vy1 = (y1 >= 0) && (y1 < Hn);
    bool vx0 = (x0 >= 0) && (x0 < Wn), vx1 = (x1 >= 0) && (x1 < Wn);
    float w00 = (vy0 && vx0) ? (1.f - wy) * (1.f - wx) : 0.f;
    float w01 = (vy0 && vx1) ? (1.f - wy) * wx : 0.f;
    float w10 = (vy1 && vx0) ? wy * (1.f - wx) : 0.f;
    float w11 = (vy1 && vx1) ? wy * wx : 0.f;
    int yc0 = min(max(y0, 0), Hn - 1), yc1 = min(max(y1, 0), Hn - 1);
    int xc0 = min(max(x0, 0), Wn - 1), xc1 = min(max(x1, 0), Wn - 1);
    // full byte offsets: q*1600 + k*512  (o*2 added in main loop)
    Sq[pl][k][0] = (yc0 * Wn + xc0) * (GROW * 2) + k * 512;
    Sq[pl][k][1] = (yc0 * Wn + xc1) * (GROW * 2) + k * 512;
    Sq[pl][k][2] = (yc1 * Wn + xc0) * (GROW * 2) + k * 512;
    Sq[pl][k][3] = (yc1 * Wn + xc1) * (GROW * 2) + k * 512;
    Sw[pl][k][0] = w00; Sw[pl][k][1] = w01; Sw[pl][k][2] = w10; Sw[pl][k][3] = w11;
  }
  __syncthreads();

  int pl = tid & 63, og = tid >> 6;
  float w[3][4]; int qb[3][4];
  #pragma unroll
  for (int k = 0; k < 3; ++k)
    #pragma unroll
    for (int cc = 0; cc < 4; ++cc) { w[k][cc] = Sw[pl][k][cc]; qb[k][cc] = Sq[pl][k][cc]; }

  float* op = out + ((size_t)b * On) * Pn + p0 + pl;
  #pragma unroll
  for (int oi = 0; oi < 2; ++oi) {
    int ob8 = o0 + og * 16 + oi * 8;       // octet base o
    float a8[8];
    #pragma unroll
    for (int e = 0; e < 8; ++e) a8[e] = 0.f;
    #pragma unroll
    for (int k = 0; k < 3; ++k)
      #pragma unroll
      for (int cc = 0; cc < 4; ++cc) {
        bf16x8 v = *(const bf16x8*)(Gb + qb[k][cc] + ob8 * 2);
        float wv = w[k][cc];
        #pragma unroll
        for (int e = 0; e < 8; ++e)
          a8[e] += wv * bf2f((unsigned short)v[e]);
      }
    #pragma unroll
    for (int e = 0; e < 8; ++e)
      op[(size_t)(ob8 + e) * Pn] = a8[e];
  }
}

extern "C" void kernel_launch(void* const* d_in, const int* in_sizes, int n_in,
                              void* d_out, int out_size, void* d_ws, size_t ws_size,
                              hipStream_t stream) {
  const float* x  = (const float*)d_in[0];
  const float* ow = (const float*)d_in[1];
  const float* ob = (const float*)d_in[2];
  const float* dw = (const float*)d_in[3];
  float* out = (float*)d_out;

  char* ws = (char*)d_ws;
  size_t wbig_bytes = (size_t)Rpad * Cn * 2;            // 459 KB
  size_t wbig_al = (wbig_bytes + 255) & ~(size_t)255;
  size_t xbT_bytes = QC * 2;                            // 8.39 MB / batch
  size_t g2_bytes  = (size_t)Pn * GROW * 2;             // 26.2 MB / batch

  int nb = (ws_size >= wbig_al + 2 * (xbT_bytes + g2_bytes)) ? 2 : 1;

  unsigned short* Wbig = (unsigned short*)ws;
  unsigned short* xbT  = (unsigned short*)(ws + wbig_al);
  unsigned short* G2   = (unsigned short*)(ws + wbig_al + (size_t)nb * xbT_bytes);

  k_wprep<<<Rpad, 256, 0, stream>>>(dw, ow, Wbig);
  for (int b0 = 0; b0 < Bn; b0 += nb) {
    k_transpose<<<dim3(256, 4, nb), 256, 0, stream>>>(x, xbT, b0);
    k_gemmG<<<dim3(128, 7, nb), 256, 0, stream>>>(xbT, Wbig, G2);
    k_epilogue<<<dim3(256, 4, nb), 256, 0, stream>>>(G2, ob, out, b0);
  }
}